// Round 1
// baseline (1360.152 us; speedup 1.0000x reference)
//
#include <hip/hip_runtime.h>
#include <math.h>

// PhyloNeighbours: per-filter (16) kNN (k=8) over 2000 features with 512-dim
// coords, then gather inputs. Distances ranked with fp32 sequential-c FMA to
// track the numpy reference's rounding; ties broken by ascending j.
//
// Scratch plan: sq (128KB) + partial top8 val/idx (16MB) live in d_out (the
// final gather overwrites all of d_out and reads none of it). Final idx
// (1MB) lives in d_ws.

#define F_TOT   2000
#define CF      16
#define KDIM    512
#define NB_K    8
#define JC      8
#define JCHUNK  250   // F_TOT / JC
#define TI      32

// LDS float offsets for the distance kernel
#define A_OFF   0               // [8 c][16 f][36] padded, i-major rows
#define B_OFF   4608            // [8 c][16 f][36]
#define E_OFF   0               // [16 i][32 j][17] (aliases A/B region by phase)
#define SQJ_OFF 9216            // [32 j][17]
#define LDS_FLOATS 9760

// ---------------------------------------------------------------- sq kernel
__global__ __launch_bounds__(256) void sq_kernel(const float* __restrict__ coords,
                                                 float* __restrict__ sq_out) {
  int i = blockIdx.x;           // 0..1999
  int t = threadIdx.x;
  int f = t & 15;
  int cg = t >> 4;              // 0..15, each covers 32 c's
  const float* base = coords + (size_t)i * CF + f;
  double s = 0.0;
  for (int c = cg * 32; c < cg * 32 + 32; ++c) {
    float v = base[(size_t)c * (F_TOT * CF)];
    s += (double)v * (double)v;
  }
  __shared__ double red[256];
  red[t] = s;
  __syncthreads();
  if (cg == 0) {
    double tot = 0.0;
#pragma unroll
    for (int g = 0; g < 16; ++g) tot += red[g * 16 + f];
    sq_out[i * CF + f] = (float)tot;
  }
}

// ---------------------------------------------- distance + partial-top8 kernel
// grid: (JC=8 j-chunks, 63 i-tiles), block 256.
// thread: f = t&15, tj = (t>>4)&3, ti = t>>6 ; per-thread 8i x 8j x 1f acc.
__global__ __launch_bounds__(256) void distk_kernel(const float* __restrict__ coords,
                                                    const float* __restrict__ sq,
                                                    float* __restrict__ pval,
                                                    int* __restrict__ pidx) {
  const int jc = blockIdx.x;          // 0..7
  const int it = blockIdx.y;          // 0..62
  const int i0 = it * TI;
  const int jbase = jc * JCHUNK;

  const int t  = threadIdx.x;
  const int f  = t & 15;
  const int tj = (t >> 4) & 3;
  const int ti = t >> 6;

  __shared__ float lds[LDS_FLOATS];

  // running sorted top-8 (ascending) per half: list h -> (i0 + 16h + (t>>4), f)
  float bval[2][NB_K];
  int   bidx[2][NB_K];
#pragma unroll
  for (int h = 0; h < 2; ++h)
#pragma unroll
    for (int k = 0; k < NB_K; ++k) { bval[h][k] = __builtin_inff(); bidx[h][k] = 0; }

  float sqi[2];
#pragma unroll
  for (int h = 0; h < 2; ++h) {
    int i = i0 + 16 * h + (t >> 4);
    sqi[h] = (i < F_TOT) ? sq[i * CF + (t & 15)] : 0.0f;
  }

  for (int jt = 0; jt < 8; ++jt) {            // j-tiles of 32 within the chunk
    const int j0 = jbase + jt * 32;
    const int jmax = (jt * 32 + 32 <= JCHUNK) ? 32 : (JCHUNK - jt * 32); // 32 or 26

    __syncthreads();  // protect sqj (read by previous tile's scan)
    if (t < 128) {    // stage sq_j for this tile: [32][17]
      int jj = t >> 2;
      int q  = t & 3;
      int jgl = j0 + jj; if (jgl > F_TOT - 1) jgl = F_TOT - 1;
      const float4 v = *(const float4*)(sq + jgl * CF + q * 4);
      float* dst = &lds[SQJ_OFF + jj * 17 + q * 4];
      dst[0] = v.x; dst[1] = v.y; dst[2] = v.z; dst[3] = v.w;
    }

    float acc[8][8];
#pragma unroll
    for (int a = 0; a < 8; ++a)
#pragma unroll
      for (int b = 0; b < 8; ++b) acc[a][b] = 0.0f;

    for (int ct = 0; ct < KDIM / 8; ++ct) {   // 64 c-tiles of 8, c ascending
      const int c0 = ct * 8;
      __syncthreads();
#pragma unroll
      for (int p = 0; p < 4; ++p) {           // stage A,B tiles (f-major, pad 36)
        int fi  = t + p * 256;                // 0..1023 float4 slots
        int cc  = fi >> 7;                    // 0..7
        int rem = fi & 127;                   // 128 float4 per c-row
        int iof = rem >> 2;                   // 0..31
        int q   = rem & 3;                    // f-group
        int ig = i0 + iof; if (ig > F_TOT - 1) ig = F_TOT - 1;
        float4 va = *(const float4*)(coords + (size_t)(c0 + cc) * (F_TOT * CF) + ig * CF + q * 4);
        float* da = &lds[A_OFF + (cc * 16 + q * 4) * 36 + iof];
        da[0] = va.x; da[36] = va.y; da[72] = va.z; da[108] = va.w;
        int jg = j0 + iof; if (jg > F_TOT - 1) jg = F_TOT - 1;
        float4 vb = *(const float4*)(coords + (size_t)(c0 + cc) * (F_TOT * CF) + jg * CF + q * 4);
        float* db = &lds[B_OFF + (cc * 16 + q * 4) * 36 + iof];
        db[0] = vb.x; db[36] = vb.y; db[72] = vb.z; db[108] = vb.w;
      }
      __syncthreads();
#pragma unroll
      for (int cc = 0; cc < 8; ++cc) {        // sequential c accumulation
        float av[8], bv[8];
        const float* ap = &lds[A_OFF + (cc * 16 + f) * 36 + ti * 8];
        const float* bp = &lds[B_OFF + (cc * 16 + f) * 36 + tj * 8];
#pragma unroll
        for (int a = 0; a < 8; ++a) av[a] = ap[a];
#pragma unroll
        for (int b = 0; b < 8; ++b) bv[b] = bp[b];
#pragma unroll
        for (int a = 0; a < 8; ++a)
#pragma unroll
          for (int b = 0; b < 8; ++b)
            acc[a][b] = fmaf(av[a], bv[b], acc[a][b]);
      }
    }

    // selection: two i-halves through LDS transpose
#pragma unroll
    for (int h = 0; h < 2; ++h) {
      __syncthreads();
      if ((ti >> 1) == h) {                   // waves owning this half write g
        int ihb = (ti & 1) * 8;
#pragma unroll
        for (int a = 0; a < 8; ++a) {
          int ih = ihb + a;
#pragma unroll
          for (int b = 0; b < 8; ++b)
            lds[E_OFF + ih * 545 + (tj * 8 + b) * 17 + f] = acc[a][b];
        }
      }
      __syncthreads();
      {
        int fl = t & 15;
        int ih = t >> 4;
        float s_i = sqi[h];
        for (int b = 0; b < jmax; ++b) {      // ascending j for tie semantics
          float g  = lds[E_OFF + ih * 545 + b * 17 + fl];
          float sj = lds[SQJ_OFF + b * 17 + fl];
          float d = fmaf(-2.0f, g, s_i + sj); // matches reference's final rounding
          d = fmaxf(d, 0.0f);
          if (d < bval[h][NB_K - 1]) {
            float cv = d; int ci = jbase + jt * 32 + b;
#pragma unroll
            for (int k = 0; k < NB_K; ++k) {
              if (cv < bval[h][k]) {
                float tv = bval[h][k]; bval[h][k] = cv; cv = tv;
                int tx = bidx[h][k]; bidx[h][k] = ci; ci = tx;
              }
            }
          }
        }
      }
    }
  }

  // write partial sorted lists
#pragma unroll
  for (int h = 0; h < 2; ++h) {
    int i = i0 + 16 * h + (t >> 4);
    if (i < F_TOT) {
      int fl = t & 15;
      size_t base = (((size_t)(i * CF + fl)) * JC + jc) * NB_K;
#pragma unroll
      for (int k = 0; k < NB_K; ++k) {
        pval[base + k] = bval[h][k];
        pidx[base + k] = bidx[h][k];
      }
    }
  }
}

// ---------------------------------------------------------------- merge kernel
__global__ __launch_bounds__(256) void merge_kernel(const float* __restrict__ pval,
                                                    const int* __restrict__ pidx,
                                                    int* __restrict__ fidx) {
  int t = blockIdx.x * 256 + threadIdx.x;   // (i*16+f), 0..31999
  if (t >= F_TOT * CF) return;
  size_t base = (size_t)t * JC * NB_K;
  int p[JC];
#pragma unroll
  for (int ch = 0; ch < JC; ++ch) p[ch] = 0;
  int i = t >> 4, fl = t & 15;
  for (int k = 0; k < NB_K; ++k) {
    float best = __builtin_inff(); int bch = 0;
#pragma unroll
    for (int ch = 0; ch < JC; ++ch) {        // ascending chunk = ascending j on ties
      if (p[ch] < NB_K) {
        float v = pval[base + ch * NB_K + p[ch]];
        if (v < best) { best = v; bch = ch; }
      }
    }
    int off = 0;
#pragma unroll
    for (int ch = 0; ch < JC; ++ch) if (ch == bch) off = ch * NB_K + p[ch];
    int jg = pidx[base + off];
#pragma unroll
    for (int ch = 0; ch < JC; ++ch) p[ch] += (ch == bch) ? 1 : 0;
    fidx[(i * NB_K + k) * CF + fl] = jg;
  }
}

// ---------------------------------------------------------------- gather kernel
__global__ __launch_bounds__(256) void gather_kernel(const float* __restrict__ inputs,
                                                     const int* __restrict__ fidx,
                                                     float* __restrict__ out) {
  int b = blockIdx.y;
  int x = blockIdx.x * 256 + threadIdx.x;    // 0..255999 = m*16+c
  int c = x & 15;
  int n = fidx[x];
  out[(size_t)b * (F_TOT * NB_K * CF) + x] =
      inputs[(size_t)b * (F_TOT * CF) + n * CF + c];
}

// ---------------------------------------------------------------- launcher
extern "C" void kernel_launch(void* const* d_in, const int* in_sizes, int n_in,
                              void* d_out, int out_size, void* d_ws, size_t ws_size,
                              hipStream_t stream) {
  const float* inputs = (const float*)d_in[0];   // (64, 2000, 16)
  const float* coords = (const float*)d_in[1];   // (512, 2000, 16)
  float* out = (float*)d_out;

  // scratch carved out of d_out (gather overwrites everything at the end)
  float* sq   = out;                          // 32000 floats
  float* pval = out + 32768;                  // 2,048,000 floats
  int*   pidx = (int*)(out + 32768 + 2048000);// 2,048,000 ints
  int*   fidx = (int*)d_ws;                   // 256,000 ints (1 MB)

  sq_kernel<<<F_TOT, 256, 0, stream>>>(coords, sq);
  dim3 g2(JC, (F_TOT + TI - 1) / TI);         // (8, 63)
  distk_kernel<<<g2, 256, 0, stream>>>(coords, sq, pval, pidx);
  merge_kernel<<<(F_TOT * CF + 255) / 256, 256, 0, stream>>>(pval, pidx, fidx);
  dim3 g4((F_TOT * NB_K * CF) / 256, 64);     // (1000, 64)
  gather_kernel<<<g4, 256, 0, stream>>>(inputs, fidx, out);
}

// Round 2
// 1333.215 us; speedup vs baseline: 1.0202x; 1.0202x over previous
//
#include <hip/hip_runtime.h>
#include <math.h>

// PhyloNeighbours: per-filter (16) kNN (k=8) over 2000 features, 512-dim coords.
// v2: bf16-MFMA approximate distances -> top-12 candidates per (i,f,j-half),
// then EXACT fp32 refinement (bit-identical to round-1 arithmetic: ascending-c
// fmaf chain, fmaf(-2,g,sqi+sqj), strict-< insert, ascending-j ties) -> gather.
//
// Memory plan:
//   d_out: phase 1 holds cbt[f][2048][512] bf16 (32 MB); phase 2 holds
//          ct[f][2000][512] fp32 (exactly out_size floats); final gather output.
//   d_ws : sq (128 KB) + cand (3 MB) + fidx (1 MB)  ~= 4.2 MB assumed available.

#define F_TOT 2000
#define CF    16
#define KDIM  512
#define NB_K  8
#define IPAD  2048
#define NCAND 12
#define NCH   2

typedef __attribute__((ext_vector_type(8))) short bf16x8;
typedef __attribute__((ext_vector_type(4))) float f32x4;

__device__ inline unsigned short f2bf(float x) {
  unsigned int u = __float_as_uint(x);
  return (unsigned short)((u + 0x7fffu + ((u >> 16) & 1u)) >> 16);
}

// ---------------------------------------------------------------- k1: sq (fp64)
__global__ __launch_bounds__(256) void sq_kernel(const float* __restrict__ coords,
                                                 float* __restrict__ sq_out) {
  int i = blockIdx.x;
  int t = threadIdx.x;
  int f = t & 15;
  int cg = t >> 4;
  const float* base = coords + (size_t)i * CF + f;
  double s = 0.0;
  for (int c = cg * 32; c < cg * 32 + 32; ++c) {
    float v = base[(size_t)c * (F_TOT * CF)];
    s += (double)v * (double)v;
  }
  __shared__ double red[256];
  red[t] = s;
  __syncthreads();
  if (cg == 0) {
    double tot = 0.0;
#pragma unroll
    for (int g = 0; g < 16; ++g) tot += red[g * 16 + f];
    sq_out[i * CF + f] = (float)tot;
  }
}

// ------------------------------------------- k2: coords -> cbt[f][i pad2048][c] bf16
__global__ __launch_bounds__(256) void cvt_bf16_kernel(const float* __restrict__ coords,
                                                       unsigned short* __restrict__ cbt) {
  __shared__ float lds[32 * 257];
  const int i0 = blockIdx.x * 16;    // 0..2032
  const int c0 = blockIdx.y * 32;
  const int t = threadIdx.x;
  const int io = t >> 4, f = t & 15;
  const int iclamp = min(i0 + io, F_TOT - 1);
  for (int cc = 0; cc < 32; ++cc)
    lds[cc * 257 + t] = coords[(size_t)(c0 + cc) * (F_TOT * CF) + iclamp * CF + f];
  __syncthreads();
  size_t obase = ((size_t)f * IPAD + (i0 + io)) * KDIM + c0;
#pragma unroll
  for (int cc = 0; cc < 32; cc += 4) {
    unsigned int lo = (unsigned int)f2bf(lds[(cc + 0) * 257 + t]) |
                      ((unsigned int)f2bf(lds[(cc + 1) * 257 + t]) << 16);
    unsigned int hi = (unsigned int)f2bf(lds[(cc + 2) * 257 + t]) |
                      ((unsigned int)f2bf(lds[(cc + 3) * 257 + t]) << 16);
    *(uint2*)(cbt + obase + cc) = make_uint2(lo, hi);
  }
}

// ------------------------------------------- k4: coords -> ct[f][i 2000][c] fp32
__global__ __launch_bounds__(256) void cvt_f32t_kernel(const float* __restrict__ coords,
                                                       float* __restrict__ ct) {
  __shared__ float lds[32 * 257];
  const int i0 = blockIdx.x * 16;    // 0..1984 (125 tiles exact)
  const int c0 = blockIdx.y * 32;
  const int t = threadIdx.x;
  const int io = t >> 4, f = t & 15;
  for (int cc = 0; cc < 32; ++cc)
    lds[cc * 257 + t] = coords[(size_t)(c0 + cc) * (F_TOT * CF) + i0 * CF + t];
  __syncthreads();
  size_t obase = ((size_t)f * F_TOT + (i0 + io)) * KDIM + c0;
#pragma unroll
  for (int cc = 0; cc < 32; cc += 4) {
    float4 v = make_float4(lds[(cc + 0) * 257 + t], lds[(cc + 1) * 257 + t],
                           lds[(cc + 2) * 257 + t], lds[(cc + 3) * 257 + t]);
    *(float4*)(ct + obase + cc) = v;
  }
}

// ------------------------------------------- k3: bf16 MFMA approx + top-12 cand
// grid 512: f = bx&15, i-tile(128) = (bx>>4)&15, j-chunk(1000) = bx>>8.
__global__ __launch_bounds__(256, 2) void approx_kernel(const unsigned short* __restrict__ cbt,
                                                        const float* __restrict__ sq,
                                                        int* __restrict__ cand) {
  const int bx = blockIdx.x;
  const int f = bx & 15;
  const int it = (bx >> 4) & 15;
  const int jc = bx >> 8;
  const int ibase = it * 128;
  const int jcbase = jc * 1000;
  const int jlimit = jcbase + 1000;   // exclusive (2000 for jc=1)

  const int t = threadIdx.x;
  const int lane = t & 63;
  const int w = t >> 6;
  const int wi = w & 1, wj = w >> 1;
  const int lrow = lane & 15, lq = lane >> 4;

  __shared__ char smem[67072];
  unsigned short* Al = (unsigned short*)smem;             // [128][72] bf16
  unsigned short* Bl = (unsigned short*)(smem + 18432);   // [256][72] bf16
  float* Dl = (float*)smem;                               // [128][129] f32 (alias)
  float* sqj = (float*)(smem + 66048);                    // [256]

  const unsigned short* abase_g = cbt + ((size_t)f * IPAD + ibase) * KDIM;

  float bv[NCAND]; int bi[NCAND];
#pragma unroll
  for (int k = 0; k < NCAND; ++k) { bv[k] = __builtin_inff(); bi[k] = 0x7fffffff; }
  float sqi = 0.0f;
  const bool scanner = (t < 128) && (ibase + t < F_TOT);
  if (scanner) sqi = sq[(ibase + t) * CF + f];

  int aoff[4], boff[8];
#pragma unroll
  for (int mi = 0; mi < 4; ++mi) aoff[mi] = (wi * 64 + mi * 16 + lrow) * 72 + lq * 8;
#pragma unroll
  for (int nj = 0; nj < 8; ++nj) boff[nj] = (wj * 128 + nj * 16 + lrow) * 72 + lq * 8;

  for (int js = 0; js < 4; ++js) {
    const int jbase = jcbase + js * 256;
    __syncthreads();
    { int jg = jbase + t; sqj[t] = (jg < F_TOT) ? sq[jg * CF + f] : 0.0f; }

    f32x4 acc[4][8];
#pragma unroll
    for (int mi = 0; mi < 4; ++mi)
#pragma unroll
      for (int nj = 0; nj < 8; ++nj) acc[mi][nj] = (f32x4){0.f, 0.f, 0.f, 0.f};

    const unsigned short* bbase_g = cbt + ((size_t)f * IPAD + jbase) * KDIM;

    for (int kc = 0; kc < 8; ++kc) {
      const int c0 = kc * 64;
      __syncthreads();
#pragma unroll
      for (int p = 0; p < 4; ++p) {           // stage A: 128 rows x 64 c
        int slot = t + p * 256;
        int row = slot >> 3, seg = slot & 7;
        uint4 v = *(const uint4*)(abase_g + (size_t)row * KDIM + c0 + seg * 8);
        *(uint4*)((char*)Al + row * 144 + seg * 16) = v;
      }
#pragma unroll
      for (int p = 0; p < 8; ++p) {           // stage B: 256 rows x 64 c
        int slot = t + p * 256;
        int row = slot >> 3, seg = slot & 7;
        uint4 v = *(const uint4*)(bbase_g + (size_t)row * KDIM + c0 + seg * 8);
        *(uint4*)((char*)Bl + row * 144 + seg * 16) = v;
      }
      __syncthreads();
#pragma unroll
      for (int ks = 0; ks < 2; ++ks) {
        const int ka = ks * 32;
        bf16x8 a[4];
#pragma unroll
        for (int mi = 0; mi < 4; ++mi) a[mi] = *(const bf16x8*)(Al + aoff[mi] + ka);
#pragma unroll
        for (int nj = 0; nj < 8; ++nj) {
          bf16x8 b = *(const bf16x8*)(Bl + boff[nj] + ka);
#pragma unroll
          for (int mi = 0; mi < 4; ++mi)
            acc[mi][nj] = __builtin_amdgcn_mfma_f32_16x16x32_bf16(a[mi], b, acc[mi][nj], 0, 0, 0);
        }
      }
    }

    // epilogue + scan: two phases of 128 j
#pragma unroll
    for (int ph = 0; ph < 2; ++ph) {
      __syncthreads();
      if (wj == ph) {                          // these waves hold block-j [ph*128, ph*128+128)
#pragma unroll
        for (int mi = 0; mi < 4; ++mi) {
          int irow = wi * 64 + mi * 16 + lq * 4;
#pragma unroll
          for (int nj = 0; nj < 8; ++nj) {
            int jcol = nj * 16 + lrow;
#pragma unroll
            for (int r = 0; r < 4; ++r)
              Dl[(irow + r) * 129 + jcol] = acc[mi][nj][r];  // C: col=lane&15, row=quad*4+reg
          }
        }
      }
      __syncthreads();
      if (scanner) {
        int j0 = jbase + ph * 128;
        int bmax = jlimit - j0; if (bmax > 128) bmax = 128;
        for (int b = 0; b < bmax; ++b) {
          float g = Dl[t * 129 + b];
          float d = fmaf(-2.0f, g, sqi + sqj[ph * 128 + b]);
          d = fmaxf(d, 0.0f);
          int jg = j0 + b;
          // lex (d, j) top-12 — approx phase only needs a superset
          if (d < bv[NCAND - 1] || (d == bv[NCAND - 1] && jg < bi[NCAND - 1])) {
            float cv = d; int ci = jg;
#pragma unroll
            for (int k = 0; k < NCAND; ++k) {
              bool lt = (cv < bv[k]) || (cv == bv[k] && ci < bi[k]);
              float tv = lt ? bv[k] : cv; int ti = lt ? bi[k] : ci;
              bv[k] = lt ? cv : bv[k];    bi[k] = lt ? ci : bi[k];
              cv = tv; ci = ti;
            }
          }
        }
      }
    }
  }

  if (scanner) {
    // sort the 12 candidate j's ascending (odd-even transposition, static idx)
#pragma unroll
    for (int r = 0; r < NCAND; ++r) {
#pragma unroll
      for (int k = 0; k + 1 < NCAND; ++k) {
        if (((k ^ r) & 1) == 0) {
          int lo = min(bi[k], bi[k + 1]);
          int hi = max(bi[k], bi[k + 1]);
          bi[k] = lo; bi[k + 1] = hi;
        }
      }
    }
    int* dst = cand + ((size_t)(ibase + t) * CF + f) * (NCAND * NCH) + jc * NCAND;
#pragma unroll
    for (int k = 0; k < NCAND; ++k) dst[k] = bi[k];
  }
}

// ------------------------------------------- k5: exact refinement (round-1 math)
__global__ __launch_bounds__(256) void refine_kernel(const float* __restrict__ ct,
                                                     const float* __restrict__ sq,
                                                     const int* __restrict__ cand,
                                                     int* __restrict__ fidx) {
  int tg = blockIdx.x * 256 + threadIdx.x;   // (i*16+f), 0..31999
  int i = tg >> 4, f = tg & 15;
  const float* a = ct + ((size_t)f * F_TOT + i) * KDIM;
  float sqi = sq[i * CF + f];
  const int* cl = cand + (size_t)tg * (NCAND * NCH);

  float bval[NB_K]; int bidx[NB_K];
#pragma unroll
  for (int k = 0; k < NB_K; ++k) { bval[k] = __builtin_inff(); bidx[k] = 0; }

  for (int m = 0; m < NCAND * NCH; m += 2) {  // candidates globally ascending in j
    int j0 = cl[m], j1 = cl[m + 1];
    const float* p = ct + ((size_t)f * F_TOT + j0) * KDIM;
    const float* q = ct + ((size_t)f * F_TOT + j1) * KDIM;
    float g0 = 0.0f, g1 = 0.0f;
    for (int c = 0; c < KDIM; c += 8) {
      float4 a0 = *(const float4*)(a + c), a1 = *(const float4*)(a + c + 4);
      float4 p0 = *(const float4*)(p + c), p1 = *(const float4*)(p + c + 4);
      float4 q0 = *(const float4*)(q + c), q1 = *(const float4*)(q + c + 4);
      g0 = fmaf(a0.x, p0.x, g0); g1 = fmaf(a0.x, q0.x, g1);
      g0 = fmaf(a0.y, p0.y, g0); g1 = fmaf(a0.y, q0.y, g1);
      g0 = fmaf(a0.z, p0.z, g0); g1 = fmaf(a0.z, q0.z, g1);
      g0 = fmaf(a0.w, p0.w, g0); g1 = fmaf(a0.w, q0.w, g1);
      g0 = fmaf(a1.x, p1.x, g0); g1 = fmaf(a1.x, q1.x, g1);
      g0 = fmaf(a1.y, p1.y, g0); g1 = fmaf(a1.y, q1.y, g1);
      g0 = fmaf(a1.z, p1.z, g0); g1 = fmaf(a1.z, q1.z, g1);
      g0 = fmaf(a1.w, p1.w, g0); g1 = fmaf(a1.w, q1.w, g1);
    }
    float d0 = fmaf(-2.0f, g0, sqi + sq[j0 * CF + f]); d0 = fmaxf(d0, 0.0f);
    float d1 = fmaf(-2.0f, g1, sqi + sq[j1 * CF + f]); d1 = fmaxf(d1, 0.0f);
    if (d0 < bval[NB_K - 1]) {
      float cv = d0; int ci = j0;
#pragma unroll
      for (int k = 0; k < NB_K; ++k)
        if (cv < bval[k]) {
          float tv = bval[k]; bval[k] = cv; cv = tv;
          int ti = bidx[k]; bidx[k] = ci; ci = ti;
        }
    }
    if (d1 < bval[NB_K - 1]) {
      float cv = d1; int ci = j1;
#pragma unroll
      for (int k = 0; k < NB_K; ++k)
        if (cv < bval[k]) {
          float tv = bval[k]; bval[k] = cv; cv = tv;
          int ti = bidx[k]; bidx[k] = ci; ci = ti;
        }
    }
  }
#pragma unroll
  for (int k = 0; k < NB_K; ++k)
    fidx[((size_t)i * NB_K + k) * CF + f] = bidx[k];
}

// ---------------------------------------------------------------- k6: gather
__global__ __launch_bounds__(256) void gather_kernel(const float* __restrict__ inputs,
                                                     const int* __restrict__ fidx,
                                                     float* __restrict__ out) {
  int b = blockIdx.y;
  int x = blockIdx.x * 256 + threadIdx.x;    // m*16+c
  int c = x & 15;
  int n = fidx[x];
  out[(size_t)b * (F_TOT * NB_K * CF) + x] =
      inputs[(size_t)b * (F_TOT * CF) + n * CF + c];
}

// ---------------------------------------------------------------- launcher
extern "C" void kernel_launch(void* const* d_in, const int* in_sizes, int n_in,
                              void* d_out, int out_size, void* d_ws, size_t ws_size,
                              hipStream_t stream) {
  const float* inputs = (const float*)d_in[0];   // (64, 2000, 16)
  const float* coords = (const float*)d_in[1];   // (512, 2000, 16)
  float* out = (float*)d_out;

  unsigned short* cbt = (unsigned short*)d_out;  // 16*2048*512 bf16 (phase 1)
  float* ct = (float*)d_out;                     // 16*2000*512 f32 (phase 2, == out_size)

  float* sq = (float*)d_ws;                      // 32768 floats
  int* cand = (int*)d_ws + 32768;                // 32000*24 ints
  int* fidx = (int*)d_ws + 32768 + 32000 * (NCAND * NCH); // 256000 ints

  sq_kernel<<<F_TOT, 256, 0, stream>>>(coords, sq);
  cvt_bf16_kernel<<<dim3(IPAD / 16, KDIM / 32), 256, 0, stream>>>(coords, cbt);
  approx_kernel<<<512, 256, 0, stream>>>(cbt, sq, cand);
  cvt_f32t_kernel<<<dim3(F_TOT / 16, KDIM / 32), 256, 0, stream>>>(coords, ct);
  refine_kernel<<<(F_TOT * CF) / 256, 256, 0, stream>>>(ct, sq, cand, fidx);
  dim3 g6((F_TOT * NB_K * CF) / 256, 64);
  gather_kernel<<<g6, 256, 0, stream>>>(inputs, fidx, out);
}

// Round 3
// 1019.494 us; speedup vs baseline: 1.3341x; 1.3077x over previous
//
#include <hip/hip_runtime.h>
#include <math.h>

// PhyloNeighbours: per-filter (16) kNN (k=8) over 2000 features, 512-dim coords.
// v3: bf16-MFMA approx distances -> global top-10 candidates per (i,f), then
// EXACT fp32 refinement parallelized over candidates (bit-compatible with the
// validated round-1/2 arithmetic: ascending-c fmaf chain, fmaf(-2,g,sqi+sqj),
// clamp, strict-< insert over ascending-j candidates) -> select -> gather.
//
// Memory plan:
//   d_out: phase 1 holds cbt[f][2048][512] bf16 (32 MB); phase 2 holds
//          ct[f][2000][512] fp32 (exactly out_size floats); final gather output.
//   d_ws : sq (128 KB) + cand (1.28 MB) + dval (1.28 MB) + fidx (1 MB) ~= 3.7 MB.

#define F_TOT 2000
#define CF    16
#define KDIM  512
#define NB_K  8
#define IPAD  2048
#define NCAND 10

typedef __attribute__((ext_vector_type(8))) short bf16x8;
typedef __attribute__((ext_vector_type(4))) float f32x4;

__device__ inline unsigned short f2bf(float x) {
  unsigned int u = __float_as_uint(x);
  return (unsigned short)((u + 0x7fffu + ((u >> 16) & 1u)) >> 16);
}

// ---------------------------------------------------------------- k1: sq (fp64)
// VALIDATED in rounds 1-2 — do not change arithmetic.
__global__ __launch_bounds__(256) void sq_kernel(const float* __restrict__ coords,
                                                 float* __restrict__ sq_out) {
  int i = blockIdx.x;
  int t = threadIdx.x;
  int f = t & 15;
  int cg = t >> 4;
  const float* base = coords + (size_t)i * CF + f;
  double s = 0.0;
  for (int c = cg * 32; c < cg * 32 + 32; ++c) {
    float v = base[(size_t)c * (F_TOT * CF)];
    s += (double)v * (double)v;
  }
  __shared__ double red[256];
  red[t] = s;
  __syncthreads();
  if (cg == 0) {
    double tot = 0.0;
#pragma unroll
    for (int g = 0; g < 16; ++g) tot += red[g * 16 + f];
    sq_out[i * CF + f] = (float)tot;
  }
}

// ------------------------------------------- k2: coords -> cbt[f][i pad2048][c] bf16
__global__ __launch_bounds__(256) void cvt_bf16_kernel(const float* __restrict__ coords,
                                                       unsigned short* __restrict__ cbt) {
  __shared__ float lds[32 * 257];
  const int i0 = blockIdx.x * 16;    // 0..2032
  const int c0 = blockIdx.y * 32;
  const int t = threadIdx.x;
  const int io = t >> 4, f = t & 15;
  const int iclamp = min(i0 + io, F_TOT - 1);
  for (int cc = 0; cc < 32; ++cc)
    lds[cc * 257 + t] = coords[(size_t)(c0 + cc) * (F_TOT * CF) + iclamp * CF + f];
  __syncthreads();
  size_t obase = ((size_t)f * IPAD + (i0 + io)) * KDIM + c0;
#pragma unroll
  for (int cc = 0; cc < 32; cc += 4) {
    unsigned int lo = (unsigned int)f2bf(lds[(cc + 0) * 257 + t]) |
                      ((unsigned int)f2bf(lds[(cc + 1) * 257 + t]) << 16);
    unsigned int hi = (unsigned int)f2bf(lds[(cc + 2) * 257 + t]) |
                      ((unsigned int)f2bf(lds[(cc + 3) * 257 + t]) << 16);
    *(uint2*)(cbt + obase + cc) = make_uint2(lo, hi);
  }
}

// ------------------------------------------- k4: coords -> ct[f][i 2000][c] fp32
__global__ __launch_bounds__(256) void cvt_f32t_kernel(const float* __restrict__ coords,
                                                       float* __restrict__ ct) {
  __shared__ float lds[32 * 257];
  const int i0 = blockIdx.x * 16;    // 0..1984 (125 tiles exact)
  const int c0 = blockIdx.y * 32;
  const int t = threadIdx.x;
  const int io = t >> 4, f = t & 15;
  for (int cc = 0; cc < 32; ++cc)
    lds[cc * 257 + t] = coords[(size_t)(c0 + cc) * (F_TOT * CF) + i0 * CF + t];
  __syncthreads();
  size_t obase = ((size_t)f * F_TOT + (i0 + io)) * KDIM + c0;
#pragma unroll
  for (int cc = 0; cc < 32; cc += 4) {
    float4 v = make_float4(lds[(cc + 0) * 257 + t], lds[(cc + 1) * 257 + t],
                           lds[(cc + 2) * 257 + t], lds[(cc + 3) * 257 + t]);
    *(float4*)(ct + obase + cc) = v;
  }
}

// ------------------------------------------- k3: bf16 MFMA approx + top-10 cand
// grid 256: f = bx&15, i-tile(128) = bx>>4. Each block scans ALL 2000 j.
__global__ __launch_bounds__(256, 2) void approx_kernel(const unsigned short* __restrict__ cbt,
                                                        const float* __restrict__ sq,
                                                        int* __restrict__ cand) {
  const int bx = blockIdx.x;
  const int f = bx & 15;
  const int it = bx >> 4;
  const int ibase = it * 128;

  const int t = threadIdx.x;
  const int lane = t & 63;
  const int w = t >> 6;
  const int wi = w & 1, wj = w >> 1;
  const int lrow = lane & 15, lq = lane >> 4;

  __shared__ char smem[67072];
  unsigned short* Al = (unsigned short*)smem;             // [128][72] bf16
  unsigned short* Bl = (unsigned short*)(smem + 18432);   // [256][72] bf16
  float* Dl = (float*)smem;                               // [128][129] f32 (alias)
  float* sqj = (float*)(smem + 66048);                    // [256]

  const unsigned short* abase_g = cbt + ((size_t)f * IPAD + ibase) * KDIM;

  float bv[NCAND]; int bi[NCAND];
#pragma unroll
  for (int k = 0; k < NCAND; ++k) { bv[k] = __builtin_inff(); bi[k] = 0x7fffffff; }
  float sqi = 0.0f;
  const bool scanner = (t < 128) && (ibase + t < F_TOT);
  if (scanner) sqi = sq[(ibase + t) * CF + f];

  int aoff[4], boff[8];
#pragma unroll
  for (int mi = 0; mi < 4; ++mi) aoff[mi] = (wi * 64 + mi * 16 + lrow) * 72 + lq * 8;
#pragma unroll
  for (int nj = 0; nj < 8; ++nj) boff[nj] = (wj * 128 + nj * 16 + lrow) * 72 + lq * 8;

  for (int js = 0; js < 8; ++js) {            // 8 x 256 j covers 2048 (pad clamped)
    const int jbase = js * 256;
    __syncthreads();
    { int jg = jbase + t; sqj[t] = (jg < F_TOT) ? sq[jg * CF + f] : 0.0f; }

    f32x4 acc[4][8];
#pragma unroll
    for (int mi = 0; mi < 4; ++mi)
#pragma unroll
      for (int nj = 0; nj < 8; ++nj) acc[mi][nj] = (f32x4){0.f, 0.f, 0.f, 0.f};

    const unsigned short* bbase_g = cbt + ((size_t)f * IPAD + jbase) * KDIM;

    for (int kc = 0; kc < 8; ++kc) {
      const int c0 = kc * 64;
      __syncthreads();
#pragma unroll
      for (int p = 0; p < 4; ++p) {           // stage A: 128 rows x 64 c
        int slot = t + p * 256;
        int row = slot >> 3, seg = slot & 7;
        uint4 v = *(const uint4*)(abase_g + (size_t)row * KDIM + c0 + seg * 8);
        *(uint4*)((char*)Al + row * 144 + seg * 16) = v;
      }
#pragma unroll
      for (int p = 0; p < 8; ++p) {           // stage B: 256 rows x 64 c
        int slot = t + p * 256;
        int row = slot >> 3, seg = slot & 7;
        uint4 v = *(const uint4*)(bbase_g + (size_t)row * KDIM + c0 + seg * 8);
        *(uint4*)((char*)Bl + row * 144 + seg * 16) = v;
      }
      __syncthreads();
#pragma unroll
      for (int ks = 0; ks < 2; ++ks) {
        const int ka = ks * 32;
        bf16x8 a[4];
#pragma unroll
        for (int mi = 0; mi < 4; ++mi) a[mi] = *(const bf16x8*)(Al + aoff[mi] + ka);
#pragma unroll
        for (int nj = 0; nj < 8; ++nj) {
          bf16x8 b = *(const bf16x8*)(Bl + boff[nj] + ka);
#pragma unroll
          for (int mi = 0; mi < 4; ++mi)
            acc[mi][nj] = __builtin_amdgcn_mfma_f32_16x16x32_bf16(a[mi], b, acc[mi][nj], 0, 0, 0);
        }
      }
    }

    // epilogue + scan: two phases of 128 j
#pragma unroll
    for (int ph = 0; ph < 2; ++ph) {
      __syncthreads();
      if (wj == ph) {                          // these waves hold block-j [ph*128, ph*128+128)
#pragma unroll
        for (int mi = 0; mi < 4; ++mi) {
          int irow = wi * 64 + mi * 16 + lq * 4;
#pragma unroll
          for (int nj = 0; nj < 8; ++nj) {
            int jcol = nj * 16 + lrow;
#pragma unroll
            for (int r = 0; r < 4; ++r)
              Dl[(irow + r) * 129 + jcol] = acc[mi][nj][r];  // C: col=lane&15, row=quad*4+reg
          }
        }
      }
      __syncthreads();
      if (scanner) {
        int j0 = jbase + ph * 128;
        int bmax = F_TOT - j0; if (bmax > 128) bmax = 128;
        for (int b = 0; b < bmax; ++b) {
          float g = Dl[t * 129 + b];
          float d = fmaf(-2.0f, g, sqi + sqj[ph * 128 + b]);
          d = fmaxf(d, 0.0f);
          int jg = j0 + b;
          // lex (d, j) top-10 — approx phase only needs a superset
          if (d < bv[NCAND - 1] || (d == bv[NCAND - 1] && jg < bi[NCAND - 1])) {
            float cv = d; int ci = jg;
#pragma unroll
            for (int k = 0; k < NCAND; ++k) {
              bool lt = (cv < bv[k]) || (cv == bv[k] && ci < bi[k]);
              float tv = lt ? bv[k] : cv; int ti = lt ? bi[k] : ci;
              bv[k] = lt ? cv : bv[k];    bi[k] = lt ? ci : bi[k];
              cv = tv; ci = ti;
            }
          }
        }
      }
    }
  }

  if (scanner) {
    // sort the 10 candidate j's ascending (odd-even transposition, static idx)
#pragma unroll
    for (int r = 0; r < NCAND; ++r) {
#pragma unroll
      for (int k = 0; k + 1 < NCAND; ++k) {
        if (((k ^ r) & 1) == 0) {
          int lo = min(bi[k], bi[k + 1]);
          int hi = max(bi[k], bi[k + 1]);
          bi[k] = lo; bi[k + 1] = hi;
        }
      }
    }
    int* dst = cand + ((size_t)(ibase + t) * CF + f) * NCAND;
#pragma unroll
    for (int k = 0; k < NCAND; ++k) dst[k] = bi[k];
  }
}

// ------------------------------------------- k5: exact distances, 2 cands/thread
// x = pf*5 + m, pf = i*16+f, candidates (2m, 2m+1). Same fmaf chain as validated.
__global__ __launch_bounds__(256) void refine_dist_kernel(const float* __restrict__ ct,
                                                          const float* __restrict__ sq,
                                                          const int* __restrict__ cand,
                                                          float* __restrict__ dval) {
  int x = blockIdx.x * 256 + threadIdx.x;    // 0..159999
  if (x >= F_TOT * CF * (NCAND / 2)) return;
  int pf = x / (NCAND / 2);
  int m = x - pf * (NCAND / 2);
  int i = pf >> 4, f = pf & 15;
  const float* a = ct + ((size_t)f * F_TOT + i) * KDIM;
  float sqi = sq[i * CF + f];
  int j0 = cand[(size_t)pf * NCAND + 2 * m];
  int j1 = cand[(size_t)pf * NCAND + 2 * m + 1];
  const float* p = ct + ((size_t)f * F_TOT + j0) * KDIM;
  const float* q = ct + ((size_t)f * F_TOT + j1) * KDIM;
  float g0 = 0.0f, g1 = 0.0f;
  for (int c = 0; c < KDIM; c += 8) {
    float4 a0 = *(const float4*)(a + c), a1 = *(const float4*)(a + c + 4);
    float4 p0 = *(const float4*)(p + c), p1 = *(const float4*)(p + c + 4);
    float4 q0 = *(const float4*)(q + c), q1 = *(const float4*)(q + c + 4);
    g0 = fmaf(a0.x, p0.x, g0); g1 = fmaf(a0.x, q0.x, g1);
    g0 = fmaf(a0.y, p0.y, g0); g1 = fmaf(a0.y, q0.y, g1);
    g0 = fmaf(a0.z, p0.z, g0); g1 = fmaf(a0.z, q0.z, g1);
    g0 = fmaf(a0.w, p0.w, g0); g1 = fmaf(a0.w, q0.w, g1);
    g0 = fmaf(a1.x, p1.x, g0); g1 = fmaf(a1.x, q1.x, g1);
    g0 = fmaf(a1.y, p1.y, g0); g1 = fmaf(a1.y, q1.y, g1);
    g0 = fmaf(a1.z, p1.z, g0); g1 = fmaf(a1.z, q1.z, g1);
    g0 = fmaf(a1.w, p1.w, g0); g1 = fmaf(a1.w, q1.w, g1);
  }
  float d0 = fmaf(-2.0f, g0, sqi + sq[j0 * CF + f]); d0 = fmaxf(d0, 0.0f);
  float d1 = fmaf(-2.0f, g1, sqi + sq[j1 * CF + f]); d1 = fmaxf(d1, 0.0f);
  dval[(size_t)pf * NCAND + 2 * m]     = d0;
  dval[(size_t)pf * NCAND + 2 * m + 1] = d1;
}

// ------------------------------------------- k6: top-8 select (ascending-j, strict <)
__global__ __launch_bounds__(256) void select_kernel(const float* __restrict__ dval,
                                                     const int* __restrict__ cand,
                                                     int* __restrict__ fidx) {
  int pf = blockIdx.x * 256 + threadIdx.x;   // (i*16+f), 0..31999
  if (pf >= F_TOT * CF) return;
  int i = pf >> 4, f = pf & 15;
  float bval[NB_K]; int bidx[NB_K];
#pragma unroll
  for (int k = 0; k < NB_K; ++k) { bval[k] = __builtin_inff(); bidx[k] = 0; }
#pragma unroll
  for (int m = 0; m < NCAND; ++m) {          // ascending j (cand sorted)
    float d = dval[(size_t)pf * NCAND + m];
    int j = cand[(size_t)pf * NCAND + m];
    if (d < bval[NB_K - 1]) {
      float cv = d; int ci = j;
#pragma unroll
      for (int k = 0; k < NB_K; ++k)
        if (cv < bval[k]) {
          float tv = bval[k]; bval[k] = cv; cv = tv;
          int ti = bidx[k]; bidx[k] = ci; ci = ti;
        }
    }
  }
#pragma unroll
  for (int k = 0; k < NB_K; ++k)
    fidx[((size_t)i * NB_K + k) * CF + f] = bidx[k];
}

// ---------------------------------------------------------------- k7: gather
__global__ __launch_bounds__(256) void gather_kernel(const float* __restrict__ inputs,
                                                     const int* __restrict__ fidx,
                                                     float* __restrict__ out) {
  int b = blockIdx.y;
  int x = blockIdx.x * 256 + threadIdx.x;    // m*16+c
  int c = x & 15;
  int n = fidx[x];
  out[(size_t)b * (F_TOT * NB_K * CF) + x] =
      inputs[(size_t)b * (F_TOT * CF) + n * CF + c];
}

// ---------------------------------------------------------------- launcher
extern "C" void kernel_launch(void* const* d_in, const int* in_sizes, int n_in,
                              void* d_out, int out_size, void* d_ws, size_t ws_size,
                              hipStream_t stream) {
  const float* inputs = (const float*)d_in[0];   // (64, 2000, 16)
  const float* coords = (const float*)d_in[1];   // (512, 2000, 16)
  float* out = (float*)d_out;

  unsigned short* cbt = (unsigned short*)d_out;  // 16*2048*512 bf16 (phase 1)
  float* ct = (float*)d_out;                     // 16*2000*512 f32 (phase 2, == out_size)

  float* sq = (float*)d_ws;                      // 32768 floats
  int* cand = (int*)d_ws + 32768;                // 32000*10 ints
  float* dval = (float*)d_ws + 32768 + 32000 * NCAND; // 32000*10 floats
  int* fidx = (int*)d_ws + 32768 + 2 * 32000 * NCAND; // 256000 ints

  sq_kernel<<<F_TOT, 256, 0, stream>>>(coords, sq);
  cvt_bf16_kernel<<<dim3(IPAD / 16, KDIM / 32), 256, 0, stream>>>(coords, cbt);
  approx_kernel<<<256, 256, 0, stream>>>(cbt, sq, cand);
  cvt_f32t_kernel<<<dim3(F_TOT / 16, KDIM / 32), 256, 0, stream>>>(coords, ct);
  refine_dist_kernel<<<(F_TOT * CF * (NCAND / 2) + 255) / 256, 256, 0, stream>>>(ct, sq, cand, dval);
  select_kernel<<<(F_TOT * CF + 255) / 256, 256, 0, stream>>>(dval, cand, fidx);
  dim3 g7((F_TOT * NB_K * CF) / 256, 64);
  gather_kernel<<<g7, 256, 0, stream>>>(inputs, fidx, out);
}